// Round 3
// baseline (347.199 us; speedup 1.0000x reference)
//
#include <hip/hip_runtime.h>

#define NUM_DEM 2
#define VOCAB 10000
#define EMB 128
#define NROWS 16384
#define ROWLEN (NUM_DEM + VOCAB)      // 10002
#define KSTEPS 313                    // ceil(10000/32)
#define PCOLS 132                     // partial row stride: 128 pooled + 1 count + pad
#define BPACK_USHORTS (KSTEPS * 4096) // 4096 bf16 per K-step tile
#define BPACK_BYTES (BPACK_USHORTS * 2)

typedef float f32x4 __attribute__((ext_vector_type(4)));
typedef __bf16 bf16x8 __attribute__((ext_vector_type(8)));
typedef short s16x8 __attribute__((ext_vector_type(8)));

union Frag {
    s16x8 s;
    bf16x8 b;
    unsigned int u[4];
    unsigned short h[8];
};

__device__ __forceinline__ unsigned short f2bf_rtne(float f) {
    unsigned int u = __float_as_uint(f);
    u += 0x7FFFu + ((u >> 16) & 1u);
    return (unsigned short)(u >> 16);
}

// ---------------- kernel 0: pack embed (fp32 -> bf16 MFMA-B fragment order) ---------
// Bpack[((t*8 + c)*64 + l)*8 + j] = bf16(embed[t*32 + (l>>4)*8 + j][c*16 + (l&15)])
__global__ void pack_embed_k(const float* __restrict__ embed,
                             unsigned short* __restrict__ bp) {
    int id = blockIdx.x * blockDim.x + threadIdx.x;
    if (id >= KSTEPS * 8 * 64) return;
    int l = id & 63;
    int c = (id >> 6) & 7;
    int t = id >> 9;
    int kbase = t * 32 + ((l >> 4) * 8);
    int n = c * 16 + (l & 15);
    unsigned short v[8];
#pragma unroll
    for (int j = 0; j < 8; ++j) {
        int k = kbase + j;
        float f = (k < VOCAB) ? embed[(size_t)k * EMB + n] : 0.0f;
        v[j] = f2bf_rtne(f);
    }
    uint4 w;
    w.x = (unsigned int)v[0] | ((unsigned int)v[1] << 16);
    w.y = (unsigned int)v[2] | ((unsigned int)v[3] << 16);
    w.z = (unsigned int)v[4] | ((unsigned int)v[5] << 16);
    w.w = (unsigned int)v[6] | ((unsigned int)v[7] << 16);
    *reinterpret_cast<uint4*>(bp + (size_t)id * 8) = w;
}

// ---------------- kernel 1: split-K masked-sum GEMM via MFMA ------------------------
// No LDS, no barriers: B fragments are loaded per-lane coalesced straight from
// bpack (L2-resident, 2.56 MB); A is streamed from HBM with a 1-step prefetch.
__global__ __launch_bounds__(256, 4) void main_gemm_k(
    const float* __restrict__ src, const unsigned short* __restrict__ bp,
    float* __restrict__ part, int nch) {
    const int tid = threadIdx.x;
    const int lane = tid & 63;
    const int wid = tid >> 6;
    const int rb = blockIdx.x & 255;  // row block: 64 rows
    const int ch = blockIdx.x >> 8;   // K chunk
    const int t0 = (KSTEPS * ch) / nch;
    const int t1 = (KSTEPS * (ch + 1)) / nch;

    const int rowbase = rb * 64 + wid * 16;
    const int arow = rowbase + (lane & 15);
    const int kgrp8 = (lane >> 4) * 8;
    const float* asrc = src + (size_t)arow * ROWLEN + NUM_DEM + kgrp8;

    f32x4 pacc[8];
#pragma unroll
    for (int f = 0; f < 8; ++f) pacc[f] = (f32x4){0.f, 0.f, 0.f, 0.f};
    f32x4 cacc = (f32x4){0.f, 0.f, 0.f, 0.f};

    Frag onesf;  // B fragment with col 0 == 1.0 (for row counts), others 0
    {
        unsigned short o = ((lane & 15) == 0) ? (unsigned short)0x3F80 : (unsigned short)0;
        unsigned int ow = (unsigned int)o | ((unsigned int)o << 16);
        onesf.u[0] = ow; onesf.u[1] = ow; onesf.u[2] = ow; onesf.u[3] = ow;
    }

    // per-lane B fragment base: bp + t*4096 + f*512 + lane*8 (ushorts)
    const s16x8* blane = reinterpret_cast<const s16x8*>(bp + (size_t)t0 * 4096 + lane * 8);

    // prefetch A for t0
    f32x4 a0n = (f32x4){0.f, 0.f, 0.f, 0.f}, a1n = a0n;
    if (t0 * 32 + kgrp8 + 8 <= VOCAB) {
        const float* ap = asrc + (size_t)t0 * 32;
        a0n = __builtin_nontemporal_load(reinterpret_cast<const f32x4*>(ap));
        a1n = __builtin_nontemporal_load(reinterpret_cast<const f32x4*>(ap + 4));
    }

    for (int t = t0; t < t1; ++t) {
        f32x4 a0 = a0n, a1 = a1n;
        // prefetch A for t+1 (10000 % 8 == 0 -> each 8-group all-valid or all-invalid)
        a0n = (f32x4){0.f, 0.f, 0.f, 0.f};
        a1n = a0n;
        if (t + 1 < t1 && (t + 1) * 32 + kgrp8 + 8 <= VOCAB) {
            const float* ap = asrc + (size_t)(t + 1) * 32;
            a0n = __builtin_nontemporal_load(reinterpret_cast<const f32x4*>(ap));
            a1n = __builtin_nontemporal_load(reinterpret_cast<const f32x4*>(ap + 4));
        }

        // B fragments: 8 independent coalesced L2 loads
        Frag bfr[8];
#pragma unroll
        for (int f = 0; f < 8; ++f) bfr[f].s = blane[f * 64];
        blane += 512;  // next K-step tile (4096 ushorts)

        Frag af;  // truncation fp32->bf16 is exact for 0.0/1.0
        af.u[0] = __builtin_amdgcn_perm(__float_as_uint(a0.y), __float_as_uint(a0.x), 0x07060302u);
        af.u[1] = __builtin_amdgcn_perm(__float_as_uint(a0.w), __float_as_uint(a0.z), 0x07060302u);
        af.u[2] = __builtin_amdgcn_perm(__float_as_uint(a1.y), __float_as_uint(a1.x), 0x07060302u);
        af.u[3] = __builtin_amdgcn_perm(__float_as_uint(a1.w), __float_as_uint(a1.z), 0x07060302u);

#pragma unroll
        for (int f = 0; f < 8; ++f)
            pacc[f] = __builtin_amdgcn_mfma_f32_16x16x32_bf16(af.b, bfr[f].b, pacc[f], 0, 0, 0);
        cacc = __builtin_amdgcn_mfma_f32_16x16x32_bf16(af.b, onesf.b, cacc, 0, 0, 0);
    }

    // epilogue: C/D layout col = lane&15, row = (lane>>4)*4 + reg
    const int rlo = (lane >> 4) * 4;
    float* pch = part + (size_t)ch * NROWS * PCOLS;
#pragma unroll
    for (int f = 0; f < 8; ++f) {
#pragma unroll
        for (int r = 0; r < 4; ++r) {
            int row = rowbase + rlo + r;
            pch[(size_t)row * PCOLS + f * 16 + (lane & 15)] = pacc[f][r];
        }
    }
    if ((lane & 15) == 0) {
#pragma unroll
        for (int r = 0; r < 4; ++r) {
            int row = rowbase + rlo + r;
            pch[(size_t)row * PCOLS + 128] = cacc[r];
        }
    }
}

// ---------------- kernel 2: reduce partials + MLP ----------------------------------
__global__ __launch_bounds__(256) void mlp_k(const float* __restrict__ part,
                                             const float* __restrict__ src,
                                             const float* __restrict__ W1,
                                             const float* __restrict__ b1,
                                             const float* __restrict__ W2,
                                             const float* __restrict__ b2,
                                             float* __restrict__ out, int nch) {
    __shared__ float xls[16][131];  // [dem(2), pooled(128)] per row
    __shared__ float hls[16][16];
    __shared__ float cnt[16];
    const int tid = threadIdx.x;
    const int rb = blockIdx.x * 16;

    if (tid < 16) {
        float s = 0.f;
        for (int c = 0; c < nch; ++c)
            s += part[((size_t)c * NROWS + rb + tid) * PCOLS + 128];
        cnt[tid] = s;
    }
    if (tid >= 16 && tid < 48) {
        int r = (tid - 16) >> 1, d = (tid - 16) & 1;
        xls[r][d] = src[(size_t)(rb + r) * ROWLEN + d];
    }
    __syncthreads();

    for (int idx = tid; idx < 16 * 128; idx += 256) {
        int r = idx >> 7, col = idx & 127;
        float s = 0.f;
        for (int c = 0; c < nch; ++c)
            s += part[((size_t)c * NROWS + rb + r) * PCOLS + col];
        xls[r][NUM_DEM + col] = s / cnt[r];
    }
    __syncthreads();

    {
        int r = tid >> 4, u = tid & 15;
        float acc = b1[u];
        for (int i = 0; i < NUM_DEM + EMB; ++i) acc += xls[r][i] * W1[i * 16 + u];
        hls[r][u] = tanhf(acc);
    }
    __syncthreads();

    if (tid < 32) {
        int r = tid >> 1, o = tid & 1;
        float acc = b2[o];
#pragma unroll
        for (int u = 0; u < 16; ++u) acc += hls[r][u] * W2[u * 2 + o];
        out[(size_t)(rb + r) * 2 + o] = acc;
    }
}

// ---------------- launch ------------------------------------------------------------
extern "C" void kernel_launch(void* const* d_in, const int* in_sizes, int n_in,
                              void* d_out, int out_size, void* d_ws, size_t ws_size,
                              hipStream_t stream) {
    const float* src = (const float*)d_in[0];
    const float* embed = (const float*)d_in[1];
    const float* W1 = (const float*)d_in[2];
    const float* b1 = (const float*)d_in[3];
    const float* W2 = (const float*)d_in[4];
    const float* b2 = (const float*)d_in[5];
    float* out = (float*)d_out;

    unsigned short* bpack = (unsigned short*)d_ws;
    float* part = (float*)((char*)d_ws + BPACK_BYTES);

    const size_t part1 = (size_t)NROWS * PCOLS * sizeof(float);
    int nch = 4;
    while (nch > 1 && BPACK_BYTES + part1 * (size_t)nch > ws_size) nch >>= 1;

    hipLaunchKernelGGL(pack_embed_k, dim3((KSTEPS * 8 * 64 + 255) / 256), dim3(256), 0,
                       stream, embed, bpack);
    hipLaunchKernelGGL(main_gemm_k, dim3(256 * nch), dim3(256), 0, stream, src, bpack,
                       part, nch);
    hipLaunchKernelGGL(mlp_k, dim3(NROWS / 16), dim3(256), 0, stream, part, src, W1, b1,
                       W2, b2, out, nch);
}

// Round 4
// 295.301 us; speedup vs baseline: 1.1757x; 1.1757x over previous
//
#include <hip/hip_runtime.h>

#define NUM_DEM 2
#define VOCAB 10000
#define EMB 128
#define NROWS 16384
#define ROWLEN (NUM_DEM + VOCAB)      // 10002
#define KSTEPS 313                    // ceil(10000/32)
#define PCOLS 132                     // partial row stride: 128 pooled + 1 count + pad
#define BPACK_USHORTS (KSTEPS * 4096) // 4096 bf16 per K-step tile
#define BPACK_BYTES (BPACK_USHORTS * 2)

typedef float f32x4 __attribute__((ext_vector_type(4)));
typedef __bf16 bf16x8 __attribute__((ext_vector_type(8)));
typedef short s16x8 __attribute__((ext_vector_type(8)));

union Frag {
    s16x8 s;
    bf16x8 b;
    unsigned int u[4];
    unsigned short h[8];
};

__device__ __forceinline__ unsigned short f2bf_rtne(float f) {
    unsigned int u = __float_as_uint(f);
    u += 0x7FFFu + ((u >> 16) & 1u);
    return (unsigned short)(u >> 16);
}

// ---------------- kernel 0: pack embed (fp32 -> bf16 MFMA-B fragment order) ---------
// Bpack[((t*8 + c)*64 + l)*8 + j] = bf16(embed[t*32 + (l>>4)*8 + j][c*16 + (l&15)])
__global__ void pack_embed_k(const float* __restrict__ embed,
                             unsigned short* __restrict__ bp) {
    int id = blockIdx.x * blockDim.x + threadIdx.x;
    if (id >= KSTEPS * 8 * 64) return;
    int l = id & 63;
    int c = (id >> 6) & 7;
    int t = id >> 9;
    int kbase = t * 32 + ((l >> 4) * 8);
    int n = c * 16 + (l & 15);
    unsigned short v[8];
#pragma unroll
    for (int j = 0; j < 8; ++j) {
        int k = kbase + j;
        float f = (k < VOCAB) ? embed[(size_t)k * EMB + n] : 0.0f;
        v[j] = f2bf_rtne(f);
    }
    uint4 w;
    w.x = (unsigned int)v[0] | ((unsigned int)v[1] << 16);
    w.y = (unsigned int)v[2] | ((unsigned int)v[3] << 16);
    w.z = (unsigned int)v[4] | ((unsigned int)v[5] << 16);
    w.w = (unsigned int)v[6] | ((unsigned int)v[7] << 16);
    *reinterpret_cast<uint4*>(bp + (size_t)id * 8) = w;
}

// ---------------- kernel 1: split-K masked-sum GEMM via MFMA ------------------------
// Counted-vmcnt pipeline: triple-buffered LDS B (staged via global_load_lds, one
// raw s_barrier per K-step, NO vmcnt(0) drain), A prefetched 2 steps ahead into
// named register slots. Steady-state wait is exactly s_waitcnt vmcnt(6):
//   issue order per body: B(t+1) x2, [fence], A(t+2) x2, [wait(6), barrier], MFMA(t)
//   -> B(t)+A(t) retired; B(t+1), A(t+1), A(t+2) (6 loads) stay in flight.
typedef const __attribute__((address_space(1))) unsigned int* gas_u32p;
typedef __attribute__((address_space(3))) unsigned int* las_u32p;
#define GLOAD_LDS16(g, l)                                                              \
    __builtin_amdgcn_global_load_lds((gas_u32p)(g), (las_u32p)(l), 16, 0, 0)

#define PIPE_BODY(T, JC, JI, BR, BW)                                                   \
    {                                                                                  \
        const int t_ = (T);                                                            \
        const int tst_ = (t_ + 1 < t1) ? (t_ + 1) : (t1 - 1);                          \
        const unsigned short* gB_ = bp + (size_t)tst_ * 4096 + wid * 1024 + lane * 8;  \
        unsigned short* lB_ = ldsB + (BW)*4096 + wid * 1024 + lane * 8;                \
        GLOAD_LDS16(gB_, lB_);                                                         \
        GLOAD_LDS16(gB_ + 512, lB_ + 512);                                             \
        asm volatile("" ::: "memory");                                                 \
        {                                                                              \
            int tld_ = (t_ + 2 < t1) ? (t_ + 2) : (t1 - 1);                            \
            int kbA_ = tld_ * 32 + kgrp8;                                              \
            const f32x4* ap_ = reinterpret_cast<const f32x4*>(                         \
                asrc + ((kbA_ + 8 <= VOCAB) ? (size_t)tld_ * 32 : (size_t)0));         \
            aS##JI##0 = __builtin_nontemporal_load(ap_);                               \
            aS##JI##1 = __builtin_nontemporal_load(ap_ + 1);                           \
        }                                                                              \
        asm volatile("s_waitcnt vmcnt(6)" ::: "memory");                               \
        __builtin_amdgcn_s_barrier();                                                  \
        {                                                                              \
            int kb_ = t_ * 32 + kgrp8;                                                 \
            bool vA_ = (kb_ + 8 <= VOCAB);                                             \
            f32x4 za_ = (f32x4){0.f, 0.f, 0.f, 0.f};                                   \
            f32x4 a0_ = vA_ ? aS##JC##0 : za_;                                         \
            f32x4 a1_ = vA_ ? aS##JC##1 : za_;                                         \
            Frag af_;                                                                  \
            af_.u[0] = __builtin_amdgcn_perm(__float_as_uint(a0_.y),                   \
                                             __float_as_uint(a0_.x), 0x07060302u);     \
            af_.u[1] = __builtin_amdgcn_perm(__float_as_uint(a0_.w),                   \
                                             __float_as_uint(a0_.z), 0x07060302u);     \
            af_.u[2] = __builtin_amdgcn_perm(__float_as_uint(a1_.y),                   \
                                             __float_as_uint(a1_.x), 0x07060302u);     \
            af_.u[3] = __builtin_amdgcn_perm(__float_as_uint(a1_.w),                   \
                                             __float_as_uint(a1_.z), 0x07060302u);     \
            const unsigned short* rB_ = ldsB + (BR)*4096 + lane * 8;                   \
            _Pragma("unroll") for (int f = 0; f < 8; ++f) {                            \
                Frag bfr_;                                                             \
                bfr_.s = *reinterpret_cast<const s16x8*>(rB_ + f * 512);               \
                pacc[f] = __builtin_amdgcn_mfma_f32_16x16x32_bf16(af_.b, bfr_.b,       \
                                                                  pacc[f], 0, 0, 0);   \
            }                                                                          \
            cacc = __builtin_amdgcn_mfma_f32_16x16x32_bf16(af_.b, onesf.b, cacc, 0, 0, \
                                                           0);                         \
        }                                                                              \
    }

__global__ __launch_bounds__(256, 3) void main_gemm_k(
    const float* __restrict__ src, const unsigned short* __restrict__ bp,
    float* __restrict__ part, int nch) {
    __shared__ alignas(16) unsigned short ldsB[3 * 4096];  // 24 KB triple buffer

    const int tid = threadIdx.x;
    const int lane = tid & 63;
    const int wid = tid >> 6;
    const int rb = blockIdx.x & 255;  // row block: 64 rows
    const int ch = blockIdx.x >> 8;   // K chunk
    const int t0 = (KSTEPS * ch) / nch;
    const int t1 = (KSTEPS * (ch + 1)) / nch;

    const int rowbase = rb * 64 + wid * 16;
    const int arow = rowbase + (lane & 15);
    const int kgrp8 = (lane >> 4) * 8;
    const float* asrc = src + (size_t)arow * ROWLEN + NUM_DEM + kgrp8;

    f32x4 pacc[8];
#pragma unroll
    for (int f = 0; f < 8; ++f) pacc[f] = (f32x4){0.f, 0.f, 0.f, 0.f};
    f32x4 cacc = (f32x4){0.f, 0.f, 0.f, 0.f};

    Frag onesf;  // B fragment with col 0 == 1.0 (for row counts), others 0
    {
        unsigned short o = ((lane & 15) == 0) ? (unsigned short)0x3F80 : (unsigned short)0;
        unsigned int ow = (unsigned int)o | ((unsigned int)o << 16);
        onesf.u[0] = ow; onesf.u[1] = ow; onesf.u[2] = ow; onesf.u[3] = ow;
    }

    f32x4 aS00, aS01, aS10, aS11, aS20, aS21;  // A slots: t, t+1, t+2 (rotating)

    // ---- prologue: B(t0)->buf0; A(t0)->slot0; A(t0+1)->slot1 (ordered by fences) ----
    {
        const unsigned short* gB_ = bp + (size_t)t0 * 4096 + wid * 1024 + lane * 8;
        unsigned short* lB_ = ldsB + wid * 1024 + lane * 8;
        GLOAD_LDS16(gB_, lB_);
        GLOAD_LDS16(gB_ + 512, lB_ + 512);
        asm volatile("" ::: "memory");
        {
            int kbA_ = t0 * 32 + kgrp8;
            const f32x4* ap_ = reinterpret_cast<const f32x4*>(
                asrc + ((kbA_ + 8 <= VOCAB) ? (size_t)t0 * 32 : (size_t)0));
            aS00 = __builtin_nontemporal_load(ap_);
            aS01 = __builtin_nontemporal_load(ap_ + 1);
        }
        asm volatile("" ::: "memory");
        {
            int t_ = t0 + 1;
            int kbA_ = t_ * 32 + kgrp8;
            const f32x4* ap_ = reinterpret_cast<const f32x4*>(
                asrc + ((kbA_ + 8 <= VOCAB) ? (size_t)t_ * 32 : (size_t)0));
            aS10 = __builtin_nontemporal_load(ap_);
            aS11 = __builtin_nontemporal_load(ap_ + 1);
        }
    }

    int t = t0;
    for (; t + 3 <= t1; t += 3) {
        PIPE_BODY(t, 0, 2, 0, 1);
        PIPE_BODY(t + 1, 1, 0, 1, 2);
        PIPE_BODY(t + 2, 2, 1, 2, 0);
    }
    if (t < t1) {  // nt % 3 == 1 (last chunk has 79 steps)
        PIPE_BODY(t, 0, 2, 0, 1);
    }

    // epilogue: C/D layout col = lane&15, row = (lane>>4)*4 + reg
    const int rlo = (lane >> 4) * 4;
    float* pch = part + (size_t)ch * NROWS * PCOLS;
#pragma unroll
    for (int f = 0; f < 8; ++f) {
#pragma unroll
        for (int r = 0; r < 4; ++r) {
            int row = rowbase + rlo + r;
            pch[(size_t)row * PCOLS + f * 16 + (lane & 15)] = pacc[f][r];
        }
    }
    if ((lane & 15) == 0) {
#pragma unroll
        for (int r = 0; r < 4; ++r) {
            int row = rowbase + rlo + r;
            pch[(size_t)row * PCOLS + 128] = cacc[r];
        }
    }
}

// ---------------- kernel 2: reduce partials + MLP ----------------------------------
__global__ __launch_bounds__(256) void mlp_k(const float* __restrict__ part,
                                             const float* __restrict__ src,
                                             const float* __restrict__ W1,
                                             const float* __restrict__ b1,
                                             const float* __restrict__ W2,
                                             const float* __restrict__ b2,
                                             float* __restrict__ out, int nch) {
    __shared__ float xls[16][131];  // [dem(2), pooled(128)] per row
    __shared__ float hls[16][16];
    __shared__ float cnt[16];
    const int tid = threadIdx.x;
    const int rb = blockIdx.x * 16;

    if (tid < 16) {
        float s = 0.f;
        for (int c = 0; c < nch; ++c)
            s += part[((size_t)c * NROWS + rb + tid) * PCOLS + 128];
        cnt[tid] = s;
    }
    if (tid >= 16 && tid < 48) {
        int r = (tid - 16) >> 1, d = (tid - 16) & 1;
        xls[r][d] = src[(size_t)(rb + r) * ROWLEN + d];
    }
    __syncthreads();

    for (int idx = tid; idx < 16 * 128; idx += 256) {
        int r = idx >> 7, col = idx & 127;
        float s = 0.f;
        for (int c = 0; c < nch; ++c)
            s += part[((size_t)c * NROWS + rb + r) * PCOLS + col];
        xls[r][NUM_DEM + col] = s / cnt[r];
    }
    __syncthreads();

    {
        int r = tid >> 4, u = tid & 15;
        float acc = b1[u];
        for (int i = 0; i < NUM_DEM + EMB; ++i) acc += xls[r][i] * W1[i * 16 + u];
        hls[r][u] = tanhf(acc);
    }
    __syncthreads();

    if (tid < 32) {
        int r = tid >> 1, o = tid & 1;
        float acc = b2[o];
#pragma unroll
        for (int u = 0; u < 16; ++u) acc += hls[r][u] * W2[u * 2 + o];
        out[(size_t)(rb + r) * 2 + o] = acc;
    }
}

// ---------------- launch ------------------------------------------------------------
extern "C" void kernel_launch(void* const* d_in, const int* in_sizes, int n_in,
                              void* d_out, int out_size, void* d_ws, size_t ws_size,
                              hipStream_t stream) {
    const float* src = (const float*)d_in[0];
    const float* embed = (const float*)d_in[1];
    const float* W1 = (const float*)d_in[2];
    const float* b1 = (const float*)d_in[3];
    const float* W2 = (const float*)d_in[4];
    const float* b2 = (const float*)d_in[5];
    float* out = (float*)d_out;

    unsigned short* bpack = (unsigned short*)d_ws;
    float* part = (float*)((char*)d_ws + BPACK_BYTES);

    const size_t part1 = (size_t)NROWS * PCOLS * sizeof(float);
    int nch = 4;
    while (nch > 1 && BPACK_BYTES + part1 * (size_t)nch > ws_size) nch >>= 1;

    hipLaunchKernelGGL(pack_embed_k, dim3((KSTEPS * 8 * 64 + 255) / 256), dim3(256), 0,
                       stream, embed, bpack);
    hipLaunchKernelGGL(main_gemm_k, dim3(256 * nch), dim3(256), 0, stream, src, bpack,
                       part, nch);
    hipLaunchKernelGGL(mlp_k, dim3(NROWS / 16), dim3(256), 0, stream, part, src, W1, b1,
                       W2, b2, out, nch);
}

// Round 5
// 294.407 us; speedup vs baseline: 1.1793x; 1.0030x over previous
//
#include <hip/hip_runtime.h>

#define NUM_DEM 2
#define VOCAB 10000
#define EMB 128
#define NROWS 16384
#define ROWLEN (NUM_DEM + VOCAB)      // 10002
#define KSTEPS 313                    // ceil(10000/32)
#define PCOLS 132                     // partial row stride: 128 pooled + 1 count + pad
#define BPACK_USHORTS (KSTEPS * 4096) // 4096 bf16 per K-step tile
#define BPACK_BYTES (BPACK_USHORTS * 2)

typedef float f32x4 __attribute__((ext_vector_type(4)));
typedef __bf16 bf16x8 __attribute__((ext_vector_type(8)));
typedef short s16x8 __attribute__((ext_vector_type(8)));

union Frag {
    s16x8 s;
    bf16x8 b;
    unsigned int u[4];
    unsigned short h[8];
};

__device__ __forceinline__ unsigned short f2bf_rtne(float f) {
    unsigned int u = __float_as_uint(f);
    u += 0x7FFFu + ((u >> 16) & 1u);
    return (unsigned short)(u >> 16);
}

// ---------------- kernel 0: pack embed (fp32 -> bf16 MFMA-B fragment order) ---------
// Bpack[((t*8 + c)*64 + l)*8 + j] = bf16(embed[t*32 + (l>>4)*8 + j][c*16 + (l&15)])
__global__ void pack_embed_k(const float* __restrict__ embed,
                             unsigned short* __restrict__ bp) {
    int id = blockIdx.x * blockDim.x + threadIdx.x;
    if (id >= KSTEPS * 8 * 64) return;
    int l = id & 63;
    int c = (id >> 6) & 7;
    int t = id >> 9;
    int kbase = t * 32 + ((l >> 4) * 8);
    int n = c * 16 + (l & 15);
    unsigned short v[8];
#pragma unroll
    for (int j = 0; j < 8; ++j) {
        int k = kbase + j;
        float f = (k < VOCAB) ? embed[(size_t)k * EMB + n] : 0.0f;
        v[j] = f2bf_rtne(f);
    }
    uint4 w;
    w.x = (unsigned int)v[0] | ((unsigned int)v[1] << 16);
    w.y = (unsigned int)v[2] | ((unsigned int)v[3] << 16);
    w.z = (unsigned int)v[4] | ((unsigned int)v[5] << 16);
    w.w = (unsigned int)v[6] | ((unsigned int)v[7] << 16);
    *reinterpret_cast<uint4*>(bp + (size_t)id * 8) = w;
}

// ---------------- kernel 1: split-K masked-sum GEMM via MFMA ------------------------
// R1 structure (known 209.9us total) with ONE change: A loads are nontemporal so
// the src stream (read-once, 655 MB) is evict-first in L2 and stops evicting the
// 2.56 MB bpack -> B staging becomes L2 hits instead of ~640 MB of HBM re-reads.
typedef const __attribute__((address_space(1))) unsigned int* gas_u32p;
typedef __attribute__((address_space(3))) unsigned int* las_u32p;
#define GLOAD_LDS16(g, l)                                                              \
    __builtin_amdgcn_global_load_lds((gas_u32p)(g), (las_u32p)(l), 16, 0, 0)

__global__ __launch_bounds__(256, 4) void main_gemm_k(
    const float* __restrict__ src, const unsigned short* __restrict__ bp,
    float* __restrict__ part, int nch) {
    __shared__ alignas(16) unsigned short ldsB[4096];  // 8 KB: one K-step B tile

    const int tid = threadIdx.x;
    const int lane = tid & 63;
    const int wid = tid >> 6;
    const int rb = blockIdx.x & 255;  // row block: 64 rows
    const int ch = blockIdx.x >> 8;   // K chunk
    const int t0 = (KSTEPS * ch) / nch;
    const int t1 = (KSTEPS * (ch + 1)) / nch;

    const int rowbase = rb * 64 + wid * 16;
    const int arow = rowbase + (lane & 15);
    const int kgrp8 = (lane >> 4) * 8;
    const float* asrc = src + (size_t)arow * ROWLEN + NUM_DEM + kgrp8;

    f32x4 pacc[8];
#pragma unroll
    for (int f = 0; f < 8; ++f) pacc[f] = (f32x4){0.f, 0.f, 0.f, 0.f};
    f32x4 cacc = (f32x4){0.f, 0.f, 0.f, 0.f};

    Frag onesf;  // B fragment with col 0 == 1.0 (for row counts), others 0
    {
        unsigned short o = ((lane & 15) == 0) ? (unsigned short)0x3F80 : (unsigned short)0;
        unsigned int ow = (unsigned int)o | ((unsigned int)o << 16);
        onesf.u[0] = ow; onesf.u[1] = ow; onesf.u[2] = ow; onesf.u[3] = ow;
    }

    for (int t = t0; t < t1; ++t) {
        // stage B tile (8 KB) into LDS: each thread 2 x 16B, linear layout
        const unsigned short* gB = bp + (size_t)t * 4096;
        GLOAD_LDS16(gB + wid * 1024 + lane * 8, ldsB + wid * 1024 + lane * 8);
        GLOAD_LDS16(gB + wid * 1024 + 512 + lane * 8, ldsB + wid * 1024 + 512 + lane * 8);

        // A: 8 consecutive fp32 (values are exactly 0.0/1.0), nontemporal (read-once)
        f32x4 a0 = (f32x4){0.f, 0.f, 0.f, 0.f}, a1 = a0;
        int kb = t * 32 + kgrp8;
        if (kb + 8 <= VOCAB) {  // 10000 % 8 == 0, so group is all-valid or all-invalid
            const f32x4* ap = reinterpret_cast<const f32x4*>(asrc + (size_t)t * 32);
            a0 = __builtin_nontemporal_load(ap);
            a1 = __builtin_nontemporal_load(ap + 1);
        }

        __syncthreads();  // B tile resident, A regs ready

        Frag af;  // truncation fp32->bf16 is exact for 0.0/1.0
        af.u[0] = __builtin_amdgcn_perm(__float_as_uint(a0.y), __float_as_uint(a0.x), 0x07060302u);
        af.u[1] = __builtin_amdgcn_perm(__float_as_uint(a0.w), __float_as_uint(a0.z), 0x07060302u);
        af.u[2] = __builtin_amdgcn_perm(__float_as_uint(a1.y), __float_as_uint(a1.x), 0x07060302u);
        af.u[3] = __builtin_amdgcn_perm(__float_as_uint(a1.w), __float_as_uint(a1.z), 0x07060302u);

#pragma unroll
        for (int f = 0; f < 8; ++f) {
            Frag bfr;
            bfr.s = *reinterpret_cast<const s16x8*>(ldsB + f * 512 + lane * 8);
            pacc[f] = __builtin_amdgcn_mfma_f32_16x16x32_bf16(af.b, bfr.b, pacc[f], 0, 0, 0);
        }
        cacc = __builtin_amdgcn_mfma_f32_16x16x32_bf16(af.b, onesf.b, cacc, 0, 0, 0);

        __syncthreads();  // protect LDS before next stage
    }

    // epilogue: C/D layout col = lane&15, row = (lane>>4)*4 + reg
    const int rlo = (lane >> 4) * 4;
    float* pch = part + (size_t)ch * NROWS * PCOLS;
#pragma unroll
    for (int f = 0; f < 8; ++f) {
#pragma unroll
        for (int r = 0; r < 4; ++r) {
            int row = rowbase + rlo + r;
            pch[(size_t)row * PCOLS + f * 16 + (lane & 15)] = pacc[f][r];
        }
    }
    if ((lane & 15) == 0) {
#pragma unroll
        for (int r = 0; r < 4; ++r) {
            int row = rowbase + rlo + r;
            pch[(size_t)row * PCOLS + 128] = cacc[r];
        }
    }
}

// ---------------- kernel 2: reduce partials + MLP ----------------------------------
__global__ __launch_bounds__(256) void mlp_k(const float* __restrict__ part,
                                             const float* __restrict__ src,
                                             const float* __restrict__ W1,
                                             const float* __restrict__ b1,
                                             const float* __restrict__ W2,
                                             const float* __restrict__ b2,
                                             float* __restrict__ out, int nch) {
    __shared__ float xls[16][131];  // [dem(2), pooled(128)] per row
    __shared__ float hls[16][16];
    __shared__ float cnt[16];
    const int tid = threadIdx.x;
    const int rb = blockIdx.x * 16;

    if (tid < 16) {
        float s = 0.f;
        for (int c = 0; c < nch; ++c)
            s += part[((size_t)c * NROWS + rb + tid) * PCOLS + 128];
        cnt[tid] = s;
    }
    if (tid >= 16 && tid < 48) {
        int r = (tid - 16) >> 1, d = (tid - 16) & 1;
        xls[r][d] = src[(size_t)(rb + r) * ROWLEN + d];
    }
    __syncthreads();

    for (int idx = tid; idx < 16 * 128; idx += 256) {
        int r = idx >> 7, col = idx & 127;
        float s = 0.f;
        for (int c = 0; c < nch; ++c)
            s += part[((size_t)c * NROWS + rb + r) * PCOLS + col];
        xls[r][NUM_DEM + col] = s / cnt[r];
    }
    __syncthreads();

    {
        int r = tid >> 4, u = tid & 15;
        float acc = b1[u];
        for (int i = 0; i < NUM_DEM + EMB; ++i) acc += xls[r][i] * W1[i * 16 + u];
        hls[r][u] = tanhf(acc);
    }
    __syncthreads();

    if (tid < 32) {
        int r = tid >> 1, o = tid & 1;
        float acc = b2[o];
#pragma unroll
        for (int u = 0; u < 16; ++u) acc += hls[r][u] * W2[u * 2 + o];
        out[(size_t)(rb + r) * 2 + o] = acc;
    }
}

// ---------------- launch ------------------------------------------------------------
extern "C" void kernel_launch(void* const* d_in, const int* in_sizes, int n_in,
                              void* d_out, int out_size, void* d_ws, size_t ws_size,
                              hipStream_t stream) {
    const float* src = (const float*)d_in[0];
    const float* embed = (const float*)d_in[1];
    const float* W1 = (const float*)d_in[2];
    const float* b1 = (const float*)d_in[3];
    const float* W2 = (const float*)d_in[4];
    const float* b2 = (const float*)d_in[5];
    float* out = (float*)d_out;

    unsigned short* bpack = (unsigned short*)d_ws;
    float* part = (float*)((char*)d_ws + BPACK_BYTES);

    const size_t part1 = (size_t)NROWS * PCOLS * sizeof(float);
    int nch = 4;
    while (nch > 1 && BPACK_BYTES + part1 * (size_t)nch > ws_size) nch >>= 1;

    hipLaunchKernelGGL(pack_embed_k, dim3((KSTEPS * 8 * 64 + 255) / 256), dim3(256), 0,
                       stream, embed, bpack);
    hipLaunchKernelGGL(main_gemm_k, dim3(256 * nch), dim3(256), 0, stream, src, bpack,
                       part, nch);
    hipLaunchKernelGGL(mlp_k, dim3(NROWS / 16), dim3(256), 0, stream, part, src, W1, b1,
                       W2, b2, out, nch);
}

// Round 6
// 203.355 us; speedup vs baseline: 1.7074x; 1.4478x over previous
//
#include <hip/hip_runtime.h>

#define NUM_DEM 2
#define VOCAB 10000
#define EMB 128
#define NROWS 16384
#define ROWLEN (NUM_DEM + VOCAB)      // 10002
#define KSTEPS 313                    // ceil(10000/32)
#define PCOLS 132                     // partial row stride: 128 pooled + 1 count + pad
#define BPACK_USHORTS (KSTEPS * 4096) // 4096 bf16 per K-step tile
#define BPACK_BYTES (BPACK_USHORTS * 2)

typedef float f32x4 __attribute__((ext_vector_type(4)));
typedef __bf16 bf16x8 __attribute__((ext_vector_type(8)));
typedef short s16x8 __attribute__((ext_vector_type(8)));

union Frag {
    s16x8 s;
    bf16x8 b;
    unsigned int u[4];
    unsigned short h[8];
};

__device__ __forceinline__ unsigned short f2bf_rtne(float f) {
    unsigned int u = __float_as_uint(f);
    u += 0x7FFFu + ((u >> 16) & 1u);
    return (unsigned short)(u >> 16);
}

// ---------------- kernel 0: pack embed (fp32 -> bf16 MFMA-B fragment order) ---------
// Bpack[((t*8 + c)*64 + l)*8 + j] = bf16(embed[t*32 + (l>>4)*8 + j][c*16 + (l&15)])
__global__ void pack_embed_k(const float* __restrict__ embed,
                             unsigned short* __restrict__ bp) {
    int id = blockIdx.x * blockDim.x + threadIdx.x;
    if (id >= KSTEPS * 8 * 64) return;
    int l = id & 63;
    int c = (id >> 6) & 7;
    int t = id >> 9;
    int kbase = t * 32 + ((l >> 4) * 8);
    int n = c * 16 + (l & 15);
    unsigned short v[8];
#pragma unroll
    for (int j = 0; j < 8; ++j) {
        int k = kbase + j;
        float f = (k < VOCAB) ? embed[(size_t)k * EMB + n] : 0.0f;
        v[j] = f2bf_rtne(f);
    }
    uint4 w;
    w.x = (unsigned int)v[0] | ((unsigned int)v[1] << 16);
    w.y = (unsigned int)v[2] | ((unsigned int)v[3] << 16);
    w.z = (unsigned int)v[4] | ((unsigned int)v[5] << 16);
    w.w = (unsigned int)v[6] | ((unsigned int)v[7] << 16);
    *reinterpret_cast<uint4*>(bp + (size_t)id * 8) = w;
}

// ---------------- kernel 1: split-K masked-sum GEMM via MFMA ------------------------
// R1 structure with ONE change: BK=64 — two K-steps per barrier pair, double-buffered
// 16 KB LDS. Halves barrier-drain frequency, doubles bytes in flight per drain.
// A loads are plain caching loads (NT proven -85us in R5).
typedef const __attribute__((address_space(1))) unsigned int* gas_u32p;
typedef __attribute__((address_space(3))) unsigned int* las_u32p;
#define GLOAD_LDS16(g, l)                                                              \
    __builtin_amdgcn_global_load_lds((gas_u32p)(g), (las_u32p)(l), 16, 0, 0)

__global__ __launch_bounds__(256, 4) void main_gemm_k(
    const float* __restrict__ src, const unsigned short* __restrict__ bp,
    float* __restrict__ part, int nch) {
    __shared__ alignas(16) unsigned short ldsB[2 * 4096];  // 16 KB: two K-step B tiles

    const int tid = threadIdx.x;
    const int lane = tid & 63;
    const int wid = tid >> 6;
    const int rb = blockIdx.x & 255;  // row block: 64 rows
    const int ch = blockIdx.x >> 8;   // K chunk
    const int t0 = (KSTEPS * ch) / nch;
    const int t1 = (KSTEPS * (ch + 1)) / nch;

    const int rowbase = rb * 64 + wid * 16;
    const int arow = rowbase + (lane & 15);
    const int kgrp8 = (lane >> 4) * 8;
    const float* asrc = src + (size_t)arow * ROWLEN + NUM_DEM + kgrp8;

    f32x4 pacc[8];
#pragma unroll
    for (int f = 0; f < 8; ++f) pacc[f] = (f32x4){0.f, 0.f, 0.f, 0.f};
    f32x4 cacc = (f32x4){0.f, 0.f, 0.f, 0.f};

    Frag onesf;  // B fragment with col 0 == 1.0 (for row counts), others 0
    {
        unsigned short o = ((lane & 15) == 0) ? (unsigned short)0x3F80 : (unsigned short)0;
        unsigned int ow = (unsigned int)o | ((unsigned int)o << 16);
        onesf.u[0] = ow; onesf.u[1] = ow; onesf.u[2] = ow; onesf.u[3] = ow;
    }

    int t = t0;
    for (; t + 2 <= t1; t += 2) {
        // stage B(t) -> buf0, B(t+1) -> buf1 (4 x 16B per thread total)
        const unsigned short* gB0 = bp + (size_t)t * 4096 + wid * 1024 + lane * 8;
        const unsigned short* gB1 = gB0 + 4096;
        unsigned short* lB0 = ldsB + wid * 1024 + lane * 8;
        unsigned short* lB1 = lB0 + 4096;
        GLOAD_LDS16(gB0, lB0);
        GLOAD_LDS16(gB0 + 512, lB0 + 512);
        GLOAD_LDS16(gB1, lB1);
        GLOAD_LDS16(gB1 + 512, lB1 + 512);

        // A(t), A(t+1): plain caching loads (values exactly 0.0/1.0)
        f32x4 z = (f32x4){0.f, 0.f, 0.f, 0.f};
        f32x4 a00 = z, a01 = z, a10 = z, a11 = z;
        if (t * 32 + kgrp8 + 8 <= VOCAB) {
            const f32x4* ap = reinterpret_cast<const f32x4*>(asrc + (size_t)t * 32);
            a00 = ap[0];
            a01 = ap[1];
        }
        if ((t + 1) * 32 + kgrp8 + 8 <= VOCAB) {
            const f32x4* ap = reinterpret_cast<const f32x4*>(asrc + (size_t)(t + 1) * 32);
            a10 = ap[0];
            a11 = ap[1];
        }

        __syncthreads();  // both B tiles resident, A regs ready

        Frag af0, af1;  // truncation fp32->bf16 is exact for 0.0/1.0
        af0.u[0] = __builtin_amdgcn_perm(__float_as_uint(a00.y), __float_as_uint(a00.x), 0x07060302u);
        af0.u[1] = __builtin_amdgcn_perm(__float_as_uint(a00.w), __float_as_uint(a00.z), 0x07060302u);
        af0.u[2] = __builtin_amdgcn_perm(__float_as_uint(a01.y), __float_as_uint(a01.x), 0x07060302u);
        af0.u[3] = __builtin_amdgcn_perm(__float_as_uint(a01.w), __float_as_uint(a01.z), 0x07060302u);
        af1.u[0] = __builtin_amdgcn_perm(__float_as_uint(a10.y), __float_as_uint(a10.x), 0x07060302u);
        af1.u[1] = __builtin_amdgcn_perm(__float_as_uint(a10.w), __float_as_uint(a10.z), 0x07060302u);
        af1.u[2] = __builtin_amdgcn_perm(__float_as_uint(a11.y), __float_as_uint(a11.x), 0x07060302u);
        af1.u[3] = __builtin_amdgcn_perm(__float_as_uint(a11.w), __float_as_uint(a11.z), 0x07060302u);

#pragma unroll
        for (int f = 0; f < 8; ++f) {
            Frag bfr;
            bfr.s = *reinterpret_cast<const s16x8*>(ldsB + f * 512 + lane * 8);
            pacc[f] = __builtin_amdgcn_mfma_f32_16x16x32_bf16(af0.b, bfr.b, pacc[f], 0, 0, 0);
        }
        cacc = __builtin_amdgcn_mfma_f32_16x16x32_bf16(af0.b, onesf.b, cacc, 0, 0, 0);
#pragma unroll
        for (int f = 0; f < 8; ++f) {
            Frag bfr;
            bfr.s = *reinterpret_cast<const s16x8*>(ldsB + 4096 + f * 512 + lane * 8);
            pacc[f] = __builtin_amdgcn_mfma_f32_16x16x32_bf16(af1.b, bfr.b, pacc[f], 0, 0, 0);
        }
        cacc = __builtin_amdgcn_mfma_f32_16x16x32_bf16(af1.b, onesf.b, cacc, 0, 0, 0);

        __syncthreads();  // protect LDS before next stage
    }
    if (t < t1) {  // odd tail (last chunk has 79 steps)
        const unsigned short* gB0 = bp + (size_t)t * 4096 + wid * 1024 + lane * 8;
        unsigned short* lB0 = ldsB + wid * 1024 + lane * 8;
        GLOAD_LDS16(gB0, lB0);
        GLOAD_LDS16(gB0 + 512, lB0 + 512);

        f32x4 z = (f32x4){0.f, 0.f, 0.f, 0.f};
        f32x4 a00 = z, a01 = z;
        if (t * 32 + kgrp8 + 8 <= VOCAB) {
            const f32x4* ap = reinterpret_cast<const f32x4*>(asrc + (size_t)t * 32);
            a00 = ap[0];
            a01 = ap[1];
        }
        __syncthreads();
        Frag af0;
        af0.u[0] = __builtin_amdgcn_perm(__float_as_uint(a00.y), __float_as_uint(a00.x), 0x07060302u);
        af0.u[1] = __builtin_amdgcn_perm(__float_as_uint(a00.w), __float_as_uint(a00.z), 0x07060302u);
        af0.u[2] = __builtin_amdgcn_perm(__float_as_uint(a01.y), __float_as_uint(a01.x), 0x07060302u);
        af0.u[3] = __builtin_amdgcn_perm(__float_as_uint(a01.w), __float_as_uint(a01.z), 0x07060302u);
#pragma unroll
        for (int f = 0; f < 8; ++f) {
            Frag bfr;
            bfr.s = *reinterpret_cast<const s16x8*>(ldsB + f * 512 + lane * 8);
            pacc[f] = __builtin_amdgcn_mfma_f32_16x16x32_bf16(af0.b, bfr.b, pacc[f], 0, 0, 0);
        }
        cacc = __builtin_amdgcn_mfma_f32_16x16x32_bf16(af0.b, onesf.b, cacc, 0, 0, 0);
        __syncthreads();
    }

    // epilogue: C/D layout col = lane&15, row = (lane>>4)*4 + reg
    const int rlo = (lane >> 4) * 4;
    float* pch = part + (size_t)ch * NROWS * PCOLS;
#pragma unroll
    for (int f = 0; f < 8; ++f) {
#pragma unroll
        for (int r = 0; r < 4; ++r) {
            int row = rowbase + rlo + r;
            pch[(size_t)row * PCOLS + f * 16 + (lane & 15)] = pacc[f][r];
        }
    }
    if ((lane & 15) == 0) {
#pragma unroll
        for (int r = 0; r < 4; ++r) {
            int row = rowbase + rlo + r;
            pch[(size_t)row * PCOLS + 128] = cacc[r];
        }
    }
}

// ---------------- kernel 2: reduce partials + MLP ----------------------------------
__global__ __launch_bounds__(256) void mlp_k(const float* __restrict__ part,
                                             const float* __restrict__ src,
                                             const float* __restrict__ W1,
                                             const float* __restrict__ b1,
                                             const float* __restrict__ W2,
                                             const float* __restrict__ b2,
                                             float* __restrict__ out, int nch) {
    __shared__ float xls[16][131];  // [dem(2), pooled(128)] per row
    __shared__ float hls[16][16];
    __shared__ float cnt[16];
    const int tid = threadIdx.x;
    const int rb = blockIdx.x * 16;

    if (tid < 16) {
        float s = 0.f;
        for (int c = 0; c < nch; ++c)
            s += part[((size_t)c * NROWS + rb + tid) * PCOLS + 128];
        cnt[tid] = s;
    }
    if (tid >= 16 && tid < 48) {
        int r = (tid - 16) >> 1, d = (tid - 16) & 1;
        xls[r][d] = src[(size_t)(rb + r) * ROWLEN + d];
    }
    __syncthreads();

    for (int idx = tid; idx < 16 * 128; idx += 256) {
        int r = idx >> 7, col = idx & 127;
        float s = 0.f;
        for (int c = 0; c < nch; ++c)
            s += part[((size_t)c * NROWS + rb + r) * PCOLS + col];
        xls[r][NUM_DEM + col] = s / cnt[r];
    }
    __syncthreads();

    {
        int r = tid >> 4, u = tid & 15;
        float acc = b1[u];
        for (int i = 0; i < NUM_DEM + EMB; ++i) acc += xls[r][i] * W1[i * 16 + u];
        hls[r][u] = tanhf(acc);
    }
    __syncthreads();

    if (tid < 32) {
        int r = tid >> 1, o = tid & 1;
        float acc = b2[o];
#pragma unroll
        for (int u = 0; u < 16; ++u) acc += hls[r][u] * W2[u * 2 + o];
        out[(size_t)(rb + r) * 2 + o] = acc;
    }
}

// ---------------- launch ------------------------------------------------------------
extern "C" void kernel_launch(void* const* d_in, const int* in_sizes, int n_in,
                              void* d_out, int out_size, void* d_ws, size_t ws_size,
                              hipStream_t stream) {
    const float* src = (const float*)d_in[0];
    const float* embed = (const float*)d_in[1];
    const float* W1 = (const float*)d_in[2];
    const float* b1 = (const float*)d_in[3];
    const float* W2 = (const float*)d_in[4];
    const float* b2 = (const float*)d_in[5];
    float* out = (float*)d_out;

    unsigned short* bpack = (unsigned short*)d_ws;
    float* part = (float*)((char*)d_ws + BPACK_BYTES);

    const size_t part1 = (size_t)NROWS * PCOLS * sizeof(float);
    int nch = 4;
    while (nch > 1 && BPACK_BYTES + part1 * (size_t)nch > ws_size) nch >>= 1;

    hipLaunchKernelGGL(pack_embed_k, dim3((KSTEPS * 8 * 64 + 255) / 256), dim3(256), 0,
                       stream, embed, bpack);
    hipLaunchKernelGGL(main_gemm_k, dim3(256 * nch), dim3(256), 0, stream, src, bpack,
                       part, nch);
    hipLaunchKernelGGL(mlp_k, dim3(NROWS / 16), dim3(256), 0, stream, part, src, W1, b1,
                       W2, b2, out, nch);
}